// Round 1
// baseline (2132.744 us; speedup 1.0000x reference)
//
#include <hip/hip_runtime.h>
#include <hip/hip_bf16.h>

typedef __bf16 bf16x8 __attribute__((ext_vector_type(8)));
typedef float  f32x4  __attribute__((ext_vector_type(4)));

#define HID 128
#define OUT 64
#define GK  192   // HID + OUT
#define BN_EPS 1e-5f

// ---------------- scatter: agg[dst] += feat[src], feat is N x 128 ----------------
__global__ __launch_bounds__(256) void scatter_add_k(
    const float* __restrict__ feat, const int* __restrict__ src,
    const int* __restrict__ dst, float* __restrict__ agg, int e)
{
  int stride = gridDim.x * blockDim.x;
  int total  = e * 32;             // 32 float4 lanes per edge
  for (int idx = blockIdx.x * blockDim.x + threadIdx.x; idx < total; idx += stride) {
    int ed = idx >> 5;
    int c  = (idx & 31) << 2;
    int s = src[ed], d = dst[ed];
    float4 v = *(const float4*)(feat + (size_t)s * HID + c);
    float* p = agg + (size_t)d * HID + c;
    atomicAdd(p + 0, v.x);
    atomicAdd(p + 1, v.y);
    atomicAdd(p + 2, v.z);
    atomicAdd(p + 3, v.w);
  }
}

// ---------------- h2a = relu(agg @ w1^T + b1), 128 -> 128 ----------------
__global__ __launch_bounds__(256) void mlp1_k(
    const float* __restrict__ agg, const float* __restrict__ w1,
    const float* __restrict__ b1, float* __restrict__ h2a, int n)
{
  __shared__ float ws[128 * 129];          // +1 dword pad: bank = (o+k)%32, conflict-free
  int t = threadIdx.x;
  for (int idx = t; idx < 128 * 128; idx += 256) {
    int o = idx >> 7, i = idx & 127;
    ws[o * 129 + i] = w1[idx];
  }
  __syncthreads();
  int j    = t & 127;
  int half = t >> 7;
  int rbase = blockIdx.x * 16;
  float bj = b1[j];
  for (int rl = half; rl < 16; rl += 2) {
    int row = rbase + rl;
    if (row >= n) break;
    const float* a = agg + (size_t)row * HID;
    float acc = bj;
    #pragma unroll 8
    for (int k = 0; k < 128; ++k) acc += a[k] * ws[j * 129 + k];
    h2a[(size_t)row * HID + j] = fmaxf(acc, 0.f);
  }
}

// ---- h = (1-eps)*(x@fc_w^T+fc_b) + eps*(agg2@w2^T+b2); also write bf16 h into G[:, :64] ----
__global__ __launch_bounds__(256) void combine_k(
    const float* __restrict__ x, const float* __restrict__ agg2,
    const float* __restrict__ fcw, const float* __restrict__ fcb,
    const float* __restrict__ w2,  const float* __restrict__ b2,
    const float* __restrict__ eps, float* __restrict__ h,
    __bf16* __restrict__ G, int n)
{
  __shared__ float fs[64 * 129];
  __shared__ float w2s[64 * 129];
  int t = threadIdx.x;
  for (int idx = t; idx < 64 * 128; idx += 256) {
    int o = idx >> 7, i = idx & 127;
    fs[o * 129 + i]  = fcw[idx];
    w2s[o * 129 + i] = w2[idx];
  }
  __syncthreads();
  int o = t & 63, q = t >> 6;
  int rbase = blockIdx.x * 32;
  float fb = fcb[o], bb = b2[o];
  for (int rl = q; rl < 32; rl += 4) {
    int row = rbase + rl;
    if (row >= n) break;
    const float* xr = x    + (size_t)row * HID;
    const float* ar = agg2 + (size_t)row * HID;
    float a1 = fb, a2 = bb;
    #pragma unroll 8
    for (int k = 0; k < 128; ++k) {
      a1 += xr[k] * fs[o * 129 + k];
      a2 += ar[k] * w2s[o * 129 + k];
    }
    float ev = eps[row];
    float hv = (1.f - ev) * a1 + ev * a2;
    h[(size_t)row * OUT + o] = hv;
    G[(size_t)row * GK + o] = (__bf16)hv;
  }
}

// ---------------- copy x (f32) into G[:, 64:192] as bf16 ----------------
__global__ __launch_bounds__(256) void xconv_k(
    const float* __restrict__ x, __bf16* __restrict__ G, int n)
{
  int stride = gridDim.x * blockDim.x;
  int total  = n * HID;
  for (int idx = blockIdx.x * blockDim.x + threadIdx.x; idx < total; idx += stride) {
    int row = idx >> 7, c = idx & 127;
    G[(size_t)row * GK + OUT + c] = (__bf16)x[idx];
  }
}

// ---------------- column sums / sumsq of h (N x 64) ----------------
__global__ __launch_bounds__(256) void stats_k(
    const float* __restrict__ h, float* __restrict__ stats, int n)
{
  int t = threadIdx.x;
  int col = t & 63, g = t >> 6;
  float s = 0.f, ss = 0.f;
  for (int row = blockIdx.x * 4 + g; row < n; row += gridDim.x * 4) {
    float v = h[(size_t)row * OUT + col];
    s += v; ss += v * v;
  }
  __shared__ float ls[256], lss[256];
  ls[t] = s; lss[t] = ss;
  __syncthreads();
  if (t < 64) {
    s  = ls[t]  + ls[t + 64]  + ls[t + 128]  + ls[t + 192];
    ss = lss[t] + lss[t + 64] + lss[t + 128] + lss[t + 192];
    atomicAdd(&stats[col], s);
    atomicAdd(&stats[64 + col], ss);
  }
}

// ---------------- hn = (h - mean) * rsqrt(var+eps) * gamma + beta ----------------
__global__ __launch_bounds__(256) void hn_k(
    const float* __restrict__ h, const float* __restrict__ stats,
    const float* __restrict__ gamma, const float* __restrict__ beta,
    float* __restrict__ outp, int n)
{
  int stride = gridDim.x * blockDim.x;
  int total  = n * OUT;
  float inv_n = 1.f / (float)n;
  for (int idx = blockIdx.x * blockDim.x + threadIdx.x; idx < total; idx += stride) {
    int col = idx & 63;
    float mean = stats[col] * inv_n;
    float var  = stats[64 + col] * inv_n - mean * mean;
    float sc   = rsqrtf(var + BN_EPS) * gamma[col];
    outp[idx] = (h[idx] - mean) * sc + beta[col];
  }
}

// ---------------- ret = 0.5 * G @ G^T, G is N x 192 bf16 ----------------
__global__ __launch_bounds__(256) void gemm_k(
    const __bf16* __restrict__ G, float* __restrict__ out, int n)
{
  __shared__ __bf16 As[128 * GK];   // 48 KB
  __shared__ __bf16 Bs[128 * GK];   // 48 KB
  int nb = n >> 7;                  // 125
  int bi = blockIdx.x / nb, bj = blockIdx.x % nb;
  int t = threadIdx.x;

  // stage both 128x192 bf16 tiles; 16B chunks; XOR-swizzle chunk index with row&7
  const uint4* ga = (const uint4*)(G + (size_t)bi * 128 * GK);
  const uint4* gb = (const uint4*)(G + (size_t)bj * 128 * GK);
  uint4* Asv = (uint4*)As;
  uint4* Bsv = (uint4*)Bs;
  #pragma unroll
  for (int it = 0; it < 12; ++it) {
    int ch = t + it * 256;          // 0..3071  (128 rows * 24 chunks)
    int row = ch / 24, c = ch % 24;
    int sw = row * 24 + (c ^ (row & 7));
    Asv[sw] = ga[ch];
    Bsv[sw] = gb[ch];
  }
  __syncthreads();

  int w = t >> 6, lane = t & 63;
  int wr = (w >> 1) << 6;           // wave's 64-row quadrant
  int wc = (w & 1) << 6;            // wave's 64-col quadrant
  int lr = lane & 15, lg = lane >> 4;
  int sx = lr & 7;

  const bf16x8* Ac = (const bf16x8*)As;
  const bf16x8* Bc = (const bf16x8*)Bs;
  f32x4 acc[4][4] = {};

  #pragma unroll
  for (int ks = 0; ks < 6; ++ks) {  // K = 192 = 6 * 32
    int chunk = (ks * 4 + lg) ^ sx;
    bf16x8 a[4], b[4];
    #pragma unroll
    for (int m = 0; m < 4; ++m) {
      a[m] = Ac[(wr + m * 16 + lr) * 24 + chunk];
      b[m] = Bc[(wc + m * 16 + lr) * 24 + chunk];
    }
    #pragma unroll
    for (int m = 0; m < 4; ++m)
      #pragma unroll
      for (int nn = 0; nn < 4; ++nn)
        acc[m][nn] = __builtin_amdgcn_mfma_f32_16x16x32_bf16(a[m], b[nn], acc[m][nn], 0, 0, 0);
  }

  size_t N = (size_t)n;
  #pragma unroll
  for (int m = 0; m < 4; ++m) {
    size_t gr0 = (size_t)(bi * 128 + wr + m * 16 + lg * 4);
    #pragma unroll
    for (int nn = 0; nn < 4; ++nn) {
      int gc = bj * 128 + wc + nn * 16 + lr;
      #pragma unroll
      for (int r = 0; r < 4; ++r)
        out[(gr0 + r) * N + gc] = acc[m][nn][r] * 0.5f;
    }
  }
}

extern "C" void kernel_launch(void* const* d_in, const int* in_sizes, int n_in,
                              void* d_out, int out_size, void* d_ws, size_t ws_size,
                              hipStream_t stream) {
  const float* x    = (const float*)d_in[0];
  const int*   src  = (const int*)d_in[1];
  const int*   dst  = (const int*)d_in[2];
  const float* fcw  = (const float*)d_in[3];
  const float* fcb  = (const float*)d_in[4];
  const float* w1   = (const float*)d_in[5];
  const float* b1   = (const float*)d_in[6];
  const float* w2   = (const float*)d_in[7];
  const float* b2   = (const float*)d_in[8];
  const float* eps  = (const float*)d_in[9];
  const float* gamma= (const float*)d_in[10];
  const float* beta = (const float*)d_in[11];
  int n = in_sizes[0] / HID;   // 16000
  int e = in_sizes[1];         // 512000
  float* out = (float*)d_out;

  char* ws = (char*)d_ws;
  size_t off = 0;
  float* agg  = (float*)(ws + off); off += (size_t)n * HID * 4;   // 8.192 MB
  float* h2a  = (float*)(ws + off); off += (size_t)n * HID * 4;   // 8.192 MB
  float* h    = (float*)(ws + off); off += (size_t)n * OUT * 4;   // 4.096 MB
  __bf16* G   = (__bf16*)(ws + off); off += (size_t)n * GK * 2;   // 6.144 MB
  float* stats= (float*)(ws + off); off += 512;

  // zero accumulators
  hipMemsetAsync(agg, 0, (size_t)n * HID * 4, stream);
  hipMemsetAsync(stats, 0, 2 * OUT * 4, stream);

  // agg = segment_sum(x[src], dst)
  scatter_add_k<<<2048, 256, 0, stream>>>(x, src, dst, agg, e);
  // h2a = relu(agg @ w1^T + b1)
  mlp1_k<<<n / 16, 256, 0, stream>>>(agg, w1, b1, h2a, n);
  // agg = segment_sum(h2a[src], dst)   (reuse buffer)
  hipMemsetAsync(agg, 0, (size_t)n * HID * 4, stream);
  scatter_add_k<<<2048, 256, 0, stream>>>(h2a, src, dst, agg, e);
  // h = (1-eps)*h1 + eps*h2 ; G[:, :64] = bf16(h)
  combine_k<<<n / 32, 256, 0, stream>>>(x, agg, fcw, fcb, w2, b2, eps, h, G, n);
  // G[:, 64:] = bf16(x)
  xconv_k<<<2048, 256, 0, stream>>>(x, G, n);
  // batch-norm stats and normalized output
  stats_k<<<256, 256, 0, stream>>>(h, stats, n);
  hn_k<<<1024, 256, 0, stream>>>(h, stats, gamma, beta, out + (size_t)n * n, n);
  // ret = 0.5 * G @ G^T
  int nb = n >> 7;
  gemm_k<<<nb * nb, 256, 0, stream>>>(G, out, n);
}

// Round 2
// 557.228 us; speedup vs baseline: 3.8274x; 3.8274x over previous
//
#include <hip/hip_runtime.h>
#include <hip/hip_bf16.h>

typedef __bf16 bf16x8 __attribute__((ext_vector_type(8)));
typedef float  f32x4  __attribute__((ext_vector_type(4)));

#define HID 128
#define OUT 64
#define GK  192   // HID + OUT
#define BN_EPS 1e-5f

// ---------------- histogram of dst ----------------
__global__ __launch_bounds__(256) void hist_k(
    const int* __restrict__ dst, int* __restrict__ cnt, int e)
{
  int stride = gridDim.x * blockDim.x;
  for (int i = blockIdx.x * blockDim.x + threadIdx.x; i < e; i += stride)
    atomicAdd(&cnt[dst[i]], 1);
}

// ---------------- single-block exclusive scan of cnt[n] -> offsets[n+1], cursor[n] ----------------
__global__ __launch_bounds__(256) void scan_k(
    const int* __restrict__ cnt, int* __restrict__ offsets,
    int* __restrict__ cursor, int n)
{
  __shared__ int part[256];
  int t = threadIdx.x;
  int chunk = (n + 255) / 256;
  int base = t * chunk;
  int s = 0;
  for (int i = 0; i < chunk; ++i) {
    int idx = base + i;
    if (idx < n) s += cnt[idx];
  }
  part[t] = s;
  __syncthreads();
  for (int off = 1; off < 256; off <<= 1) {
    int v = 0;
    if (t >= off) v = part[t - off];
    __syncthreads();
    if (t >= off) part[t] += v;
    __syncthreads();
  }
  int run = (t == 0) ? 0 : part[t - 1];
  for (int i = 0; i < chunk; ++i) {
    int idx = base + i;
    if (idx < n) {
      offsets[idx] = run;
      cursor[idx]  = run;
      run += cnt[idx];
    }
  }
  if (t == 255) offsets[n] = run;
}

// ---------------- place src ids into dst-sorted order ----------------
__global__ __launch_bounds__(256) void place_k(
    const int* __restrict__ src, const int* __restrict__ dst,
    int* __restrict__ cursor, int* __restrict__ sorted_src, int e)
{
  int stride = gridDim.x * blockDim.x;
  for (int i = blockIdx.x * blockDim.x + threadIdx.x; i < e; i += stride) {
    int pos = atomicAdd(&cursor[dst[i]], 1);
    sorted_src[pos] = src[i];
  }
}

// ---------------- agg[d] = sum over segment of feat[sorted_src[i]], one wave per d ----------------
__global__ __launch_bounds__(256) void agg_k(
    const float* __restrict__ feat, const int* __restrict__ sorted_src,
    const int* __restrict__ offsets, float* __restrict__ agg, int n)
{
  int wave = (blockIdx.x * 256 + threadIdx.x) >> 6;
  int lane = threadIdx.x & 63;
  if (wave >= n) return;
  int beg = offsets[wave], end = offsets[wave + 1];
  float ax = 0.f, ay = 0.f;
  int i = beg;
  for (; i + 1 < end; i += 2) {
    int s0 = sorted_src[i], s1 = sorted_src[i + 1];
    float2 v0 = *(const float2*)(feat + (size_t)s0 * HID + lane * 2);
    float2 v1 = *(const float2*)(feat + (size_t)s1 * HID + lane * 2);
    ax += v0.x + v1.x;
    ay += v0.y + v1.y;
  }
  if (i < end) {
    int s0 = sorted_src[i];
    float2 v0 = *(const float2*)(feat + (size_t)s0 * HID + lane * 2);
    ax += v0.x; ay += v0.y;
  }
  float2 r; r.x = ax; r.y = ay;
  *(float2*)(agg + (size_t)wave * HID + lane * 2) = r;
}

// ---------------- h2a = relu(agg @ w1^T + b1), 128 -> 128 ----------------
__global__ __launch_bounds__(256) void mlp1_k(
    const float* __restrict__ agg, const float* __restrict__ w1,
    const float* __restrict__ b1, float* __restrict__ h2a, int n)
{
  __shared__ float ws[128 * 129];
  int t = threadIdx.x;
  for (int idx = t; idx < 128 * 128; idx += 256) {
    int o = idx >> 7, i = idx & 127;
    ws[o * 129 + i] = w1[idx];
  }
  __syncthreads();
  int j    = t & 127;
  int half = t >> 7;
  int rbase = blockIdx.x * 16;
  float bj = b1[j];
  for (int rl = half; rl < 16; rl += 2) {
    int row = rbase + rl;
    if (row >= n) break;
    const float* a = agg + (size_t)row * HID;
    float acc = bj;
    #pragma unroll 8
    for (int k = 0; k < 128; ++k) acc += a[k] * ws[j * 129 + k];
    h2a[(size_t)row * HID + j] = fmaxf(acc, 0.f);
  }
}

// ---- h = (1-eps)*(x@fc_w^T+fc_b) + eps*(agg2@w2^T+b2); also write bf16 h into G[:, :64] ----
__global__ __launch_bounds__(256) void combine_k(
    const float* __restrict__ x, const float* __restrict__ agg2,
    const float* __restrict__ fcw, const float* __restrict__ fcb,
    const float* __restrict__ w2,  const float* __restrict__ b2,
    const float* __restrict__ eps, float* __restrict__ h,
    __bf16* __restrict__ G, int n)
{
  __shared__ float fs[64 * 129];
  __shared__ float w2s[64 * 129];
  int t = threadIdx.x;
  for (int idx = t; idx < 64 * 128; idx += 256) {
    int o = idx >> 7, i = idx & 127;
    fs[o * 129 + i]  = fcw[idx];
    w2s[o * 129 + i] = w2[idx];
  }
  __syncthreads();
  int o = t & 63, q = t >> 6;
  int rbase = blockIdx.x * 32;
  float fb = fcb[o], bb = b2[o];
  for (int rl = q; rl < 32; rl += 4) {
    int row = rbase + rl;
    if (row >= n) break;
    const float* xr = x    + (size_t)row * HID;
    const float* ar = agg2 + (size_t)row * HID;
    float a1 = fb, a2 = bb;
    #pragma unroll 8
    for (int k = 0; k < 128; ++k) {
      a1 += xr[k] * fs[o * 129 + k];
      a2 += ar[k] * w2s[o * 129 + k];
    }
    float ev = eps[row];
    float hv = (1.f - ev) * a1 + ev * a2;
    h[(size_t)row * OUT + o] = hv;
    G[(size_t)row * GK + o] = (__bf16)hv;
  }
}

// ---------------- copy x (f32) into G[:, 64:192] as bf16 ----------------
__global__ __launch_bounds__(256) void xconv_k(
    const float* __restrict__ x, __bf16* __restrict__ G, int n)
{
  int stride = gridDim.x * blockDim.x;
  int total  = n * HID;
  for (int idx = blockIdx.x * blockDim.x + threadIdx.x; idx < total; idx += stride) {
    int row = idx >> 7, c = idx & 127;
    G[(size_t)row * GK + OUT + c] = (__bf16)x[idx];
  }
}

// ---------------- column sums / sumsq of h (N x 64) ----------------
__global__ __launch_bounds__(256) void stats_k(
    const float* __restrict__ h, float* __restrict__ stats, int n)
{
  int t = threadIdx.x;
  int col = t & 63, g = t >> 6;
  float s = 0.f, ss = 0.f;
  for (int row = blockIdx.x * 4 + g; row < n; row += gridDim.x * 4) {
    float v = h[(size_t)row * OUT + col];
    s += v; ss += v * v;
  }
  __shared__ float ls[256], lss[256];
  ls[t] = s; lss[t] = ss;
  __syncthreads();
  if (t < 64) {
    s  = ls[t]  + ls[t + 64]  + ls[t + 128]  + ls[t + 192];
    ss = lss[t] + lss[t + 64] + lss[t + 128] + lss[t + 192];
    atomicAdd(&stats[col], s);
    atomicAdd(&stats[64 + col], ss);
  }
}

// ---------------- hn = (h - mean) * rsqrt(var+eps) * gamma + beta ----------------
__global__ __launch_bounds__(256) void hn_k(
    const float* __restrict__ h, const float* __restrict__ stats,
    const float* __restrict__ gamma, const float* __restrict__ beta,
    float* __restrict__ outp, int n)
{
  int stride = gridDim.x * blockDim.x;
  int total  = n * OUT;
  float inv_n = 1.f / (float)n;
  for (int idx = blockIdx.x * blockDim.x + threadIdx.x; idx < total; idx += stride) {
    int col = idx & 63;
    float mean = stats[col] * inv_n;
    float var  = stats[64 + col] * inv_n - mean * mean;
    float sc   = rsqrtf(var + BN_EPS) * gamma[col];
    outp[idx] = (h[idx] - mean) * sc + beta[col];
  }
}

// ---------------- ret = 0.5 * G @ G^T, G is N x 192 bf16 ----------------
__global__ __launch_bounds__(256) void gemm_k(
    const __bf16* __restrict__ G, float* __restrict__ out, int n)
{
  __shared__ __bf16 As[128 * GK];   // 48 KB
  __shared__ __bf16 Bs[128 * GK];   // 48 KB
  int nb = n >> 7;                  // 125
  int bi = blockIdx.x / nb, bj = blockIdx.x % nb;
  int t = threadIdx.x;

  const uint4* ga = (const uint4*)(G + (size_t)bi * 128 * GK);
  const uint4* gb = (const uint4*)(G + (size_t)bj * 128 * GK);
  uint4* Asv = (uint4*)As;
  uint4* Bsv = (uint4*)Bs;
  #pragma unroll
  for (int it = 0; it < 12; ++it) {
    int ch = t + it * 256;
    int row = ch / 24, c = ch % 24;
    int sw = row * 24 + (c ^ (row & 7));
    Asv[sw] = ga[ch];
    Bsv[sw] = gb[ch];
  }
  __syncthreads();

  int w = t >> 6, lane = t & 63;
  int wr = (w >> 1) << 6;
  int wc = (w & 1) << 6;
  int lr = lane & 15, lg = lane >> 4;
  int sx = lr & 7;

  const bf16x8* Ac = (const bf16x8*)As;
  const bf16x8* Bc = (const bf16x8*)Bs;
  f32x4 acc[4][4] = {};

  #pragma unroll
  for (int ks = 0; ks < 6; ++ks) {
    int chunk = (ks * 4 + lg) ^ sx;
    bf16x8 a[4], b[4];
    #pragma unroll
    for (int m = 0; m < 4; ++m) {
      a[m] = Ac[(wr + m * 16 + lr) * 24 + chunk];
      b[m] = Bc[(wc + m * 16 + lr) * 24 + chunk];
    }
    #pragma unroll
    for (int m = 0; m < 4; ++m)
      #pragma unroll
      for (int nn = 0; nn < 4; ++nn)
        acc[m][nn] = __builtin_amdgcn_mfma_f32_16x16x32_bf16(a[m], b[nn], acc[m][nn], 0, 0, 0);
  }

  size_t N = (size_t)n;
  #pragma unroll
  for (int m = 0; m < 4; ++m) {
    size_t gr0 = (size_t)(bi * 128 + wr + m * 16 + lg * 4);
    #pragma unroll
    for (int nn = 0; nn < 4; ++nn) {
      int gc = bj * 128 + wc + nn * 16 + lr;
      #pragma unroll
      for (int r = 0; r < 4; ++r)
        out[(gr0 + r) * N + gc] = acc[m][nn][r] * 0.5f;
    }
  }
}

extern "C" void kernel_launch(void* const* d_in, const int* in_sizes, int n_in,
                              void* d_out, int out_size, void* d_ws, size_t ws_size,
                              hipStream_t stream) {
  const float* x    = (const float*)d_in[0];
  const int*   src  = (const int*)d_in[1];
  const int*   dst  = (const int*)d_in[2];
  const float* fcw  = (const float*)d_in[3];
  const float* fcb  = (const float*)d_in[4];
  const float* w1   = (const float*)d_in[5];
  const float* b1   = (const float*)d_in[6];
  const float* w2   = (const float*)d_in[7];
  const float* b2   = (const float*)d_in[8];
  const float* eps  = (const float*)d_in[9];
  const float* gamma= (const float*)d_in[10];
  const float* beta = (const float*)d_in[11];
  int n = in_sizes[0] / HID;   // 16000
  int e = in_sizes[1];         // 512000
  float* out = (float*)d_out;

  char* ws = (char*)d_ws;
  size_t off = 0;
  float* agg   = (float*)(ws + off); off += (size_t)n * HID * 4;   // 8.192 MB
  float* h2a   = (float*)(ws + off); off += (size_t)n * HID * 4;   // 8.192 MB
  float* h     = (float*)(ws + off); off += (size_t)n * OUT * 4;   // 4.096 MB
  __bf16* G    = (__bf16*)(ws + off); off += (size_t)n * GK * 2;   // 6.144 MB
  float* stats = (float*)(ws + off); off += 512;
  int* cnt     = (int*)(ws + off); off += (size_t)n * 4;
  int* offsets = (int*)(ws + off); off += (size_t)(n + 1) * 4;
  int* cursor  = (int*)(ws + off); off += (size_t)n * 4;
  int* sorted_src = (int*)(ws + off); off += (size_t)e * 4;

  hipMemsetAsync(cnt, 0, (size_t)n * 4, stream);
  hipMemsetAsync(stats, 0, 2 * OUT * 4, stream);

  // ---- counting sort of edges by dst (once; reused by both aggregations) ----
  hist_k<<<512, 256, 0, stream>>>(dst, cnt, e);
  scan_k<<<1, 256, 0, stream>>>(cnt, offsets, cursor, n);
  place_k<<<512, 256, 0, stream>>>(src, dst, cursor, sorted_src, e);

  // ---- agg = segment_sum(x[src], dst) ----
  agg_k<<<(n * 64 + 255) / 256, 256, 0, stream>>>(x, sorted_src, offsets, agg, n);
  // h2a = relu(agg @ w1^T + b1)
  mlp1_k<<<n / 16, 256, 0, stream>>>(agg, w1, b1, h2a, n);
  // ---- agg = segment_sum(h2a[src], dst) ----
  agg_k<<<(n * 64 + 255) / 256, 256, 0, stream>>>(h2a, sorted_src, offsets, agg, n);
  // h = (1-eps)*h1 + eps*h2 ; G[:, :64] = bf16(h)
  combine_k<<<n / 32, 256, 0, stream>>>(x, agg, fcw, fcb, w2, b2, eps, h, G, n);
  // G[:, 64:] = bf16(x)
  xconv_k<<<2048, 256, 0, stream>>>(x, G, n);
  // batch-norm stats and normalized output
  stats_k<<<256, 256, 0, stream>>>(h, stats, n);
  hn_k<<<1024, 256, 0, stream>>>(h, stats, gamma, beta, out + (size_t)n * n, n);
  // ret = 0.5 * G @ G^T
  int nb = n >> 7;
  gemm_k<<<nb * nb, 256, 0, stream>>>(G, out, n);
}

// Round 3
// 501.414 us; speedup vs baseline: 4.2535x; 1.1113x over previous
//
#include <hip/hip_runtime.h>
#include <hip/hip_bf16.h>

typedef __bf16 bf16x8 __attribute__((ext_vector_type(8)));
typedef float  f32x4  __attribute__((ext_vector_type(4)));

#define HID 128
#define OUT 64
#define GK  192   // HID + OUT
#define BN_EPS 1e-5f

// ---------------- histogram of dst ----------------
__global__ __launch_bounds__(256) void hist_k(
    const int* __restrict__ dst, int* __restrict__ cnt, int e)
{
  int stride = gridDim.x * blockDim.x;
  for (int i = blockIdx.x * blockDim.x + threadIdx.x; i < e; i += stride)
    atomicAdd(&cnt[dst[i]], 1);
}

// ---------------- single-block exclusive scan ----------------
__global__ __launch_bounds__(256) void scan_k(
    const int* __restrict__ cnt, int* __restrict__ offsets,
    int* __restrict__ cursor, int n)
{
  __shared__ int part[256];
  int t = threadIdx.x;
  int chunk = (n + 255) / 256;
  int base = t * chunk;
  int s = 0;
  for (int i = 0; i < chunk; ++i) {
    int idx = base + i;
    if (idx < n) s += cnt[idx];
  }
  part[t] = s;
  __syncthreads();
  for (int off = 1; off < 256; off <<= 1) {
    int v = 0;
    if (t >= off) v = part[t - off];
    __syncthreads();
    if (t >= off) part[t] += v;
    __syncthreads();
  }
  int run = (t == 0) ? 0 : part[t - 1];
  for (int i = 0; i < chunk; ++i) {
    int idx = base + i;
    if (idx < n) {
      offsets[idx] = run;
      cursor[idx]  = run;
      run += cnt[idx];
    }
  }
  if (t == 255) offsets[n] = run;
}

// ---------------- place src ids into dst-sorted order ----------------
__global__ __launch_bounds__(256) void place_k(
    const int* __restrict__ src, const int* __restrict__ dst,
    int* __restrict__ cursor, int* __restrict__ sorted_src, int e)
{
  int stride = gridDim.x * blockDim.x;
  for (int i = blockIdx.x * blockDim.x + threadIdx.x; i < e; i += stride) {
    int pos = atomicAdd(&cursor[dst[i]], 1);
    sorted_src[pos] = src[i];
  }
}

// ---- agg[d] = segment sum; one wave per d; 2 edges in flight (32 lanes x float4) ----
__global__ __launch_bounds__(256) void agg_k(
    const float* __restrict__ feat, const int* __restrict__ sorted_src,
    const int* __restrict__ offsets, float* __restrict__ agg, int n)
{
  int wave = (blockIdx.x * 256 + threadIdx.x) >> 6;
  int lane = threadIdx.x & 63;
  if (wave >= n) return;
  int half = lane >> 5;        // which edge of the pair this half-wave handles
  int l32  = lane & 31;
  int beg = offsets[wave], end = offsets[wave + 1];
  f32x4 acc = {0.f, 0.f, 0.f, 0.f};
  for (int i = beg + half; i < end; i += 2) {
    int s = sorted_src[i];
    acc += *(const f32x4*)(feat + (size_t)s * HID + l32 * 4);
  }
  // combine the two half-wave partials (same columns in lane and lane^32)
  f32x4 other;
  #pragma unroll
  for (int j = 0; j < 4; ++j) other[j] = __shfl_xor(acc[j], 32, 64);
  acc += other;
  if (half == 0)
    *(f32x4*)(agg + (size_t)wave * HID + l32 * 4) = acc;
}

// ---------------- h2a = relu(agg @ w1^T + b1), 128 -> 128 ----------------
__global__ __launch_bounds__(256) void mlp1_k(
    const float* __restrict__ agg, const float* __restrict__ w1,
    const float* __restrict__ b1, float* __restrict__ h2a, int n)
{
  __shared__ f32x4 ws4[128 * 33];    // stride 33 f4s: bank-floor-optimal
  int t = threadIdx.x;
  const f32x4* w1v = (const f32x4*)w1;
  for (int idx = t; idx < 128 * 32; idx += 256) {
    int r = idx >> 5, c = idx & 31;
    ws4[r * 33 + c] = w1v[idx];
  }
  __syncthreads();
  int j = t & 127, half = t >> 7;
  int rbase = blockIdx.x * 16;
  float bj = b1[j];
  for (int rl = half; rl < 16; rl += 2) {
    int row = rbase + rl;
    const f32x4* a4 = (const f32x4*)(agg + (size_t)row * HID);
    float acc = bj;
    #pragma unroll
    for (int k = 0; k < 32; ++k) {
      f32x4 w = ws4[j * 33 + k], a = a4[k];
      acc += w[0] * a[0] + w[1] * a[1] + w[2] * a[2] + w[3] * a[3];
    }
    h2a[(size_t)row * HID + j] = fmaxf(acc, 0.f);
  }
}

// ---- h = (1-eps)*(x@fc_w^T+fc_b) + eps*(agg2@w2^T+b2); G[:,0:64]=bf16(h);
//      G[:,64:192]=bf16(x); BN partial stats via atomics ----
__global__ __launch_bounds__(256) void combine_k(
    const float* __restrict__ x, const float* __restrict__ agg2,
    const float* __restrict__ fcw, const float* __restrict__ fcb,
    const float* __restrict__ w2,  const float* __restrict__ b2,
    const float* __restrict__ eps, float* __restrict__ h,
    __bf16* __restrict__ G, float* __restrict__ stats, int n)
{
  __shared__ f32x4 fs4[64 * 33];
  __shared__ f32x4 w2s4[64 * 33];
  __shared__ float ls[256], lss[256];
  int t = threadIdx.x;
  const f32x4* fv = (const f32x4*)fcw;
  const f32x4* wv = (const f32x4*)w2;
  for (int idx = t; idx < 64 * 32; idx += 256) {
    int r = idx >> 5, c = idx & 31;
    fs4[r * 33 + c]  = fv[idx];
    w2s4[r * 33 + c] = wv[idx];
  }
  __syncthreads();
  int o = t & 63, q = t >> 6;
  int rbase = blockIdx.x * 32;
  float fb = fcb[o], bb = b2[o];
  float s = 0.f, ss = 0.f;
  for (int rl = q; rl < 32; rl += 4) {
    int row = rbase + rl;
    const f32x4* x4 = (const f32x4*)(x    + (size_t)row * HID);
    const f32x4* g4 = (const f32x4*)(agg2 + (size_t)row * HID);
    float a1 = fb, a2 = bb;
    #pragma unroll
    for (int k = 0; k < 32; ++k) {
      f32x4 wf = fs4[o * 33 + k],  xv = x4[k];
      f32x4 ww = w2s4[o * 33 + k], gv = g4[k];
      a1 += wf[0] * xv[0] + wf[1] * xv[1] + wf[2] * xv[2] + wf[3] * xv[3];
      a2 += ww[0] * gv[0] + ww[1] * gv[1] + ww[2] * gv[2] + ww[3] * gv[3];
    }
    float ev = eps[row];
    float hv = (1.f - ev) * a1 + ev * a2;
    h[(size_t)row * OUT + o] = hv;
    G[(size_t)row * GK + o] = (__bf16)hv;
    s += hv; ss += hv * hv;
  }
  // fold xconv: G[:,64:192] = bf16(x) for this block's 32 rows
  for (int idx = t; idx < 32 * 64; idx += 256) {
    int rr = idx >> 6, cp = idx & 63;
    int row = rbase + rr;
    float2 xv = *(const float2*)(x + (size_t)row * HID + cp * 2);
    G[(size_t)row * GK + OUT + cp * 2]     = (__bf16)xv.x;
    G[(size_t)row * GK + OUT + cp * 2 + 1] = (__bf16)xv.y;
  }
  // BN partial stats
  ls[t] = s; lss[t] = ss;
  __syncthreads();
  if (t < 64) {
    s  = ls[t]  + ls[t + 64]  + ls[t + 128]  + ls[t + 192];
    ss = lss[t] + lss[t + 64] + lss[t + 128] + lss[t + 192];
    atomicAdd(&stats[t], s);
    atomicAdd(&stats[64 + t], ss);
  }
}

// ---------------- hn = (h - mean) * rsqrt(var+eps) * gamma + beta ----------------
__global__ __launch_bounds__(256) void hn_k(
    const float* __restrict__ h, const float* __restrict__ stats,
    const float* __restrict__ gamma, const float* __restrict__ beta,
    float* __restrict__ outp, int n)
{
  int stride = gridDim.x * blockDim.x;
  int total  = n * OUT;
  float inv_n = 1.f / (float)n;
  for (int idx = blockIdx.x * blockDim.x + threadIdx.x; idx < total; idx += stride) {
    int col = idx & 63;
    float mean = stats[col] * inv_n;
    float var  = stats[64 + col] * inv_n - mean * mean;
    float sc   = rsqrtf(var + BN_EPS) * gamma[col];
    outp[idx] = (h[idx] - mean) * sc + beta[col];
  }
}

// ---- ret = 0.5 * G @ G^T, symmetric: only bi<=bj computed; mirror via LDS transpose ----
__global__ __launch_bounds__(256) void gemm_k(
    const __bf16* __restrict__ G, float* __restrict__ out, int n)
{
  __shared__ __bf16 As[128 * 64];   // 16 KB, BK=64 chunk, XOR-swizzled
  __shared__ __bf16 Bs[128 * 64];   // 16 KB
  __shared__ float  T[64 * 132];    // 33.8 KB transpose staging (stride 132 floats)
  int nb = n >> 7;                  // 125
  int bid = blockIdx.x;
  int bi = 0, rem = bid;
  while (rem >= nb - bi) { rem -= nb - bi; ++bi; }   // triangular decode, bi <= bj
  int bj = bi + rem;
  int t = threadIdx.x;
  int w = t >> 6, lane = t & 63;
  int wr = (w >> 1) << 6;           // wave row quadrant (0/64)
  int wc = (w & 1) << 6;            // wave col quadrant (0/64)
  int lr = lane & 15, lg = lane >> 4;

  const uint4* ga = (const uint4*)(G + (size_t)bi * 128 * GK);
  const uint4* gb = (const uint4*)(G + (size_t)bj * 128 * GK);
  uint4* Asv = (uint4*)As;
  uint4* Bsv = (uint4*)Bs;

  f32x4 acc[4][4] = {};
  #pragma unroll
  for (int kc = 0; kc < 3; ++kc) {  // K = 192 = 3 * 64
    #pragma unroll
    for (int it = 0; it < 4; ++it) {
      int ch = t + it * 256;        // 0..1023: 128 rows x 8 f4-chunks
      int row = ch >> 3, c = ch & 7;
      int sw = row * 8 + (c ^ (row & 7));
      int gidx = row * 24 + kc * 8 + c;
      Asv[sw] = ga[gidx];
      Bsv[sw] = gb[gidx];
    }
    __syncthreads();
    const bf16x8* Ac = (const bf16x8*)As;
    const bf16x8* Bc = (const bf16x8*)Bs;
    #pragma unroll
    for (int ks = 0; ks < 2; ++ks) {
      bf16x8 a[4], b[4];
      #pragma unroll
      for (int m = 0; m < 4; ++m) {
        int ar = wr + m * 16 + lr;
        int br = wc + m * 16 + lr;
        a[m] = Ac[ar * 8 + ((ks * 4 + lg) ^ (ar & 7))];
        b[m] = Bc[br * 8 + ((ks * 4 + lg) ^ (br & 7))];
      }
      #pragma unroll
      for (int m = 0; m < 4; ++m)
        #pragma unroll
        for (int nn = 0; nn < 4; ++nn)
          acc[m][nn] = __builtin_amdgcn_mfma_f32_16x16x32_bf16(a[m], b[nn], acc[m][nn], 0, 0, 0);
    }
    __syncthreads();
  }

  #pragma unroll
  for (int m = 0; m < 4; ++m)
    #pragma unroll
    for (int nn = 0; nn < 4; ++nn)
      acc[m][nn] = acc[m][nn] * 0.5f;

  size_t N = (size_t)n;

  // mirrored tile (bj,bi) via LDS transpose, two 64-row passes (skip on diagonal)
  if (bi != bj) {
    #pragma unroll
    for (int p = 0; p < 2; ++p) {
      if ((wc >> 6) == p) {
        #pragma unroll
        for (int m = 0; m < 4; ++m)
          #pragma unroll
          for (int nn = 0; nn < 4; ++nn) {
            int c  = nn * 16 + lr;            // local col within this 64-half
            int r0 = wr + m * 16 + lg * 4;    // original row
            *(f32x4*)&T[c * 132 + r0] = acc[m][nn];
          }
      }
      __syncthreads();
      #pragma unroll
      for (int it = 0; it < 8; ++it) {
        int idx = t + it * 256;               // 64 rows x 32 f4
        int rr = idx >> 5, c4 = idx & 31;
        f32x4 v = *(const f32x4*)&T[rr * 132 + c4 * 4];
        *(f32x4*)&out[(size_t)(bj * 128 + p * 64 + rr) * N + bi * 128 + c4 * 4] = v;
      }
      __syncthreads();
    }
  }

  // direct tile (bi,bj) from registers (16-col 64B runs)
  #pragma unroll
  for (int m = 0; m < 4; ++m) {
    size_t gr0 = (size_t)(bi * 128 + wr + m * 16 + lg * 4);
    #pragma unroll
    for (int nn = 0; nn < 4; ++nn) {
      int gc = bj * 128 + wc + nn * 16 + lr;
      #pragma unroll
      for (int r = 0; r < 4; ++r)
        out[(gr0 + r) * N + gc] = acc[m][nn][r];
    }
  }
}

extern "C" void kernel_launch(void* const* d_in, const int* in_sizes, int n_in,
                              void* d_out, int out_size, void* d_ws, size_t ws_size,
                              hipStream_t stream) {
  const float* x    = (const float*)d_in[0];
  const int*   src  = (const int*)d_in[1];
  const int*   dst  = (const int*)d_in[2];
  const float* fcw  = (const float*)d_in[3];
  const float* fcb  = (const float*)d_in[4];
  const float* w1   = (const float*)d_in[5];
  const float* b1   = (const float*)d_in[6];
  const float* w2   = (const float*)d_in[7];
  const float* b2   = (const float*)d_in[8];
  const float* eps  = (const float*)d_in[9];
  const float* gamma= (const float*)d_in[10];
  const float* beta = (const float*)d_in[11];
  int n = in_sizes[0] / HID;   // 16000
  int e = in_sizes[1];         // 512000
  float* out = (float*)d_out;

  char* ws = (char*)d_ws;
  size_t off = 0;
  float* agg   = (float*)(ws + off); off += (size_t)n * HID * 4;
  float* h2a   = (float*)(ws + off); off += (size_t)n * HID * 4;
  float* h     = (float*)(ws + off); off += (size_t)n * OUT * 4;
  __bf16* G    = (__bf16*)(ws + off); off += (size_t)n * GK * 2;
  float* stats = (float*)(ws + off); off += 512;
  int* cnt     = (int*)(ws + off); off += (size_t)n * 4;
  int* offsets = (int*)(ws + off); off += (size_t)(n + 1) * 4;
  int* cursor  = (int*)(ws + off); off += (size_t)n * 4;
  int* sorted_src = (int*)(ws + off); off += (size_t)e * 4;

  hipMemsetAsync(cnt, 0, (size_t)n * 4, stream);
  hipMemsetAsync(stats, 0, 2 * OUT * 4, stream);

  // counting sort of edges by dst (once; reused by both aggregations)
  hist_k<<<512, 256, 0, stream>>>(dst, cnt, e);
  scan_k<<<1, 256, 0, stream>>>(cnt, offsets, cursor, n);
  place_k<<<512, 256, 0, stream>>>(src, dst, cursor, sorted_src, e);

  // agg = segment_sum(x[src], dst)
  agg_k<<<(n * 64 + 255) / 256, 256, 0, stream>>>(x, sorted_src, offsets, agg, n);
  // h2a = relu(agg @ w1^T + b1)
  mlp1_k<<<n / 16, 256, 0, stream>>>(agg, w1, b1, h2a, n);
  // agg = segment_sum(h2a[src], dst)
  agg_k<<<(n * 64 + 255) / 256, 256, 0, stream>>>(h2a, sorted_src, offsets, agg, n);
  // h, G, BN stats, xconv fused
  combine_k<<<n / 32, 256, 0, stream>>>(x, agg, fcw, fcb, w2, b2, eps, h, G, stats, n);
  // normalized output
  hn_k<<<1024, 256, 0, stream>>>(h, stats, gamma, beta, out + (size_t)n * n, n);
  // ret = 0.5 * G @ G^T (symmetric, triangular grid)
  int nb = n >> 7;
  gemm_k<<<nb * (nb + 1) / 2, 256, 0, stream>>>(G, out, n);
}

// Round 4
// 487.108 us; speedup vs baseline: 4.3784x; 1.0294x over previous
//
#include <hip/hip_runtime.h>
#include <hip/hip_bf16.h>

typedef __bf16 bf16x8 __attribute__((ext_vector_type(8)));
typedef float  f32x4  __attribute__((ext_vector_type(4)));

#define HID 128
#define OUT 64
#define GK  192   // HID + OUT
#define BN_EPS 1e-5f

// ---------------- histogram of dst ----------------
__global__ __launch_bounds__(256) void hist_k(
    const int* __restrict__ dst, int* __restrict__ cnt, int e)
{
  int stride = gridDim.x * blockDim.x;
  for (int i = blockIdx.x * blockDim.x + threadIdx.x; i < e; i += stride)
    atomicAdd(&cnt[dst[i]], 1);
}

// ---------------- single-block exclusive scan ----------------
__global__ __launch_bounds__(256) void scan_k(
    const int* __restrict__ cnt, int* __restrict__ offsets,
    int* __restrict__ cursor, int n)
{
  __shared__ int part[256];
  int t = threadIdx.x;
  int chunk = (n + 255) / 256;
  int base = t * chunk;
  int s = 0;
  for (int i = 0; i < chunk; ++i) {
    int idx = base + i;
    if (idx < n) s += cnt[idx];
  }
  part[t] = s;
  __syncthreads();
  for (int off = 1; off < 256; off <<= 1) {
    int v = 0;
    if (t >= off) v = part[t - off];
    __syncthreads();
    if (t >= off) part[t] += v;
    __syncthreads();
  }
  int run = (t == 0) ? 0 : part[t - 1];
  for (int i = 0; i < chunk; ++i) {
    int idx = base + i;
    if (idx < n) {
      offsets[idx] = run;
      cursor[idx]  = run;
      run += cnt[idx];
    }
  }
  if (t == 255) offsets[n] = run;
}

// ---------------- place src ids into dst-sorted order ----------------
__global__ __launch_bounds__(256) void place_k(
    const int* __restrict__ src, const int* __restrict__ dst,
    int* __restrict__ cursor, int* __restrict__ sorted_src, int e)
{
  int stride = gridDim.x * blockDim.x;
  for (int i = blockIdx.x * blockDim.x + threadIdx.x; i < e; i += stride) {
    int pos = atomicAdd(&cursor[dst[i]], 1);
    sorted_src[pos] = src[i];
  }
}

// ---- agg[d] = segment sum; one wave per d; 4 gathers in flight (2 per half-wave) ----
__global__ __launch_bounds__(256) void agg_k(
    const float* __restrict__ feat, const int* __restrict__ sorted_src,
    const int* __restrict__ offsets, float* __restrict__ agg, int n)
{
  int wave = (blockIdx.x * 256 + threadIdx.x) >> 6;
  int lane = threadIdx.x & 63;
  if (wave >= n) return;
  int half = lane >> 5;
  int l32  = lane & 31;
  int beg = offsets[wave], end = offsets[wave + 1];
  f32x4 a0 = {0.f, 0.f, 0.f, 0.f}, a1 = {0.f, 0.f, 0.f, 0.f};
  int i = beg + half;
  for (; i + 2 < end; i += 4) {
    int s0 = sorted_src[i];
    int s1 = sorted_src[i + 2];
    a0 += *(const f32x4*)(feat + (size_t)s0 * HID + l32 * 4);
    a1 += *(const f32x4*)(feat + (size_t)s1 * HID + l32 * 4);
  }
  if (i < end) {
    int s0 = sorted_src[i];
    a0 += *(const f32x4*)(feat + (size_t)s0 * HID + l32 * 4);
  }
  a0 += a1;
  f32x4 other;
  #pragma unroll
  for (int j = 0; j < 4; ++j) other[j] = __shfl_xor(a0[j], 32, 64);
  a0 += other;
  if (half == 0)
    *(f32x4*)(agg + (size_t)wave * HID + l32 * 4) = a0;
}

// ---------------- h2a = relu(agg @ w1^T + b1), 128 -> 128 ----------------
__global__ __launch_bounds__(256) void mlp1_k(
    const float* __restrict__ agg, const float* __restrict__ w1,
    const float* __restrict__ b1, float* __restrict__ h2a, int n)
{
  __shared__ f32x4 ws4[128 * 33];
  int t = threadIdx.x;
  const f32x4* w1v = (const f32x4*)w1;
  for (int idx = t; idx < 128 * 32; idx += 256) {
    int r = idx >> 5, c = idx & 31;
    ws4[r * 33 + c] = w1v[idx];
  }
  __syncthreads();
  int j = t & 127, half = t >> 7;
  int rbase = blockIdx.x * 16;
  float bj = b1[j];
  for (int rl = half; rl < 16; rl += 2) {
    int row = rbase + rl;
    const f32x4* a4 = (const f32x4*)(agg + (size_t)row * HID);
    float acc = bj;
    #pragma unroll
    for (int k = 0; k < 32; ++k) {
      f32x4 w = ws4[j * 33 + k], a = a4[k];
      acc += w[0] * a[0] + w[1] * a[1] + w[2] * a[2] + w[3] * a[3];
    }
    h2a[(size_t)row * HID + j] = fmaxf(acc, 0.f);
  }
}

// ---- h = (1-eps)*(x@fc_w^T+fc_b) + eps*(agg2@w2^T+b2); G[:,0:64]=bf16(h);
//      G[:,64:192]=bf16(x); BN partial stats via atomics ----
__global__ __launch_bounds__(256) void combine_k(
    const float* __restrict__ x, const float* __restrict__ agg2,
    const float* __restrict__ fcw, const float* __restrict__ fcb,
    const float* __restrict__ w2,  const float* __restrict__ b2,
    const float* __restrict__ eps, float* __restrict__ h,
    __bf16* __restrict__ G, float* __restrict__ stats, int n)
{
  __shared__ f32x4 fs4[64 * 33];
  __shared__ f32x4 w2s4[64 * 33];
  __shared__ float ls[256], lss[256];
  int t = threadIdx.x;
  const f32x4* fv = (const f32x4*)fcw;
  const f32x4* wv = (const f32x4*)w2;
  for (int idx = t; idx < 64 * 32; idx += 256) {
    int r = idx >> 5, c = idx & 31;
    fs4[r * 33 + c]  = fv[idx];
    w2s4[r * 33 + c] = wv[idx];
  }
  __syncthreads();
  int o = t & 63, q = t >> 6;
  int rbase = blockIdx.x * 32;
  float fb = fcb[o], bb = b2[o];
  float s = 0.f, ss = 0.f;
  for (int rl = q; rl < 32; rl += 4) {
    int row = rbase + rl;
    const f32x4* x4 = (const f32x4*)(x    + (size_t)row * HID);
    const f32x4* g4 = (const f32x4*)(agg2 + (size_t)row * HID);
    float a1 = fb, a2 = bb;
    #pragma unroll
    for (int k = 0; k < 32; ++k) {
      f32x4 wf = fs4[o * 33 + k],  xv = x4[k];
      f32x4 ww = w2s4[o * 33 + k], gv = g4[k];
      a1 += wf[0] * xv[0] + wf[1] * xv[1] + wf[2] * xv[2] + wf[3] * xv[3];
      a2 += ww[0] * gv[0] + ww[1] * gv[1] + ww[2] * gv[2] + ww[3] * gv[3];
    }
    float ev = eps[row];
    float hv = (1.f - ev) * a1 + ev * a2;
    h[(size_t)row * OUT + o] = hv;
    G[(size_t)row * GK + o] = (__bf16)hv;
    s += hv; ss += hv * hv;
  }
  for (int idx = t; idx < 32 * 64; idx += 256) {
    int rr = idx >> 6, cp = idx & 63;
    int row = rbase + rr;
    float2 xv = *(const float2*)(x + (size_t)row * HID + cp * 2);
    G[(size_t)row * GK + OUT + cp * 2]     = (__bf16)xv.x;
    G[(size_t)row * GK + OUT + cp * 2 + 1] = (__bf16)xv.y;
  }
  ls[t] = s; lss[t] = ss;
  __syncthreads();
  if (t < 64) {
    s  = ls[t]  + ls[t + 64]  + ls[t + 128]  + ls[t + 192];
    ss = lss[t] + lss[t + 64] + lss[t + 128] + lss[t + 192];
    atomicAdd(&stats[t], s);
    atomicAdd(&stats[64 + t], ss);
  }
}

// ---------------- hn = (h - mean) * rsqrt(var+eps) * gamma + beta ----------------
__global__ __launch_bounds__(256) void hn_k(
    const float* __restrict__ h, const float* __restrict__ stats,
    const float* __restrict__ gamma, const float* __restrict__ beta,
    float* __restrict__ outp, int n)
{
  int stride = gridDim.x * blockDim.x;
  int total  = n * OUT;
  float inv_n = 1.f / (float)n;
  for (int idx = blockIdx.x * blockDim.x + threadIdx.x; idx < total; idx += stride) {
    int col = idx & 63;
    float mean = stats[col] * inv_n;
    float var  = stats[64 + col] * inv_n - mean * mean;
    float sc   = rsqrtf(var + BN_EPS) * gamma[col];
    outp[idx] = (h[idx] - mean) * sc + beta[col];
  }
}

// ---- ret = 0.5 * G @ G^T, symmetric (bi<=bj); LDS pool aliases As/Bs with T ----
__global__ __launch_bounds__(256, 3) void gemm_k(
    const __bf16* __restrict__ G, float* __restrict__ out, int n, int nwg)
{
  __shared__ char pool[64 * 132 * 4];          // 33.8 KB: As(16K)+Bs(16K) then T
  __bf16* As = (__bf16*)pool;
  __bf16* Bs = (__bf16*)(pool + 16384);
  float*  T  = (float*)pool;

  int nb = n >> 7;                  // 125
  // XCD-chunked bijective swizzle (m204): contiguous tile runs per XCD
  int orig = blockIdx.x;
  int q = nwg >> 3, r = nwg & 7;
  int xcd = orig & 7, idx8 = orig >> 3;
  int bid = (xcd < r ? xcd * (q + 1) : r * (q + 1) + (xcd - r) * q) + idx8;

  int bi = 0, rem = bid;
  while (rem >= nb - bi) { rem -= nb - bi; ++bi; }   // triangular decode, bi <= bj
  int bj = bi + rem;
  int t = threadIdx.x;
  int w = t >> 6, lane = t & 63;
  int wr = (w >> 1) << 6;
  int wc = (w & 1) << 6;
  int lr = lane & 15, lg = lane >> 4;

  const uint4* ga = (const uint4*)(G + (size_t)bi * 128 * GK);
  const uint4* gb = (const uint4*)(G + (size_t)bj * 128 * GK);
  uint4* Asv = (uint4*)As;
  uint4* Bsv = (uint4*)Bs;

  f32x4 acc[4][4] = {};
  #pragma unroll
  for (int kc = 0; kc < 3; ++kc) {  // K = 192 = 3 * 64
    #pragma unroll
    for (int it = 0; it < 4; ++it) {
      int ch = t + it * 256;
      int row = ch >> 3, c = ch & 7;
      int sw = row * 8 + (c ^ (row & 7));
      int gidx = row * 24 + kc * 8 + c;
      Asv[sw] = ga[gidx];
      Bsv[sw] = gb[gidx];
    }
    __syncthreads();
    const bf16x8* Ac = (const bf16x8*)As;
    const bf16x8* Bc = (const bf16x8*)Bs;
    #pragma unroll
    for (int ks = 0; ks < 2; ++ks) {
      bf16x8 a[4], b[4];
      #pragma unroll
      for (int m = 0; m < 4; ++m) {
        int ar = wr + m * 16 + lr;
        int br = wc + m * 16 + lr;
        a[m] = Ac[ar * 8 + ((ks * 4 + lg) ^ (ar & 7))];
        b[m] = Bc[br * 8 + ((ks * 4 + lg) ^ (br & 7))];
      }
      #pragma unroll
      for (int m = 0; m < 4; ++m)
        #pragma unroll
        for (int nn = 0; nn < 4; ++nn)
          acc[m][nn] = __builtin_amdgcn_mfma_f32_16x16x32_bf16(a[m], b[nn], acc[m][nn], 0, 0, 0);
    }
    __syncthreads();                // also guards As/Bs before T aliasing reuse
  }

  #pragma unroll
  for (int m = 0; m < 4; ++m)
    #pragma unroll
    for (int nn = 0; nn < 4; ++nn)
      acc[m][nn] = acc[m][nn] * 0.5f;

  size_t N = (size_t)n;

  // mirrored tile (bj,bi) via LDS transpose over the aliased pool
  if (bi != bj) {
    #pragma unroll
    for (int p = 0; p < 2; ++p) {
      if ((wc >> 6) == p) {
        #pragma unroll
        for (int m = 0; m < 4; ++m)
          #pragma unroll
          for (int nn = 0; nn < 4; ++nn) {
            int c  = nn * 16 + lr;
            int r0 = wr + m * 16 + lg * 4;
            *(f32x4*)&T[c * 132 + r0] = acc[m][nn];
          }
      }
      __syncthreads();
      #pragma unroll
      for (int it = 0; it < 8; ++it) {
        int idx = t + it * 256;
        int rr = idx >> 5, c4 = idx & 31;
        f32x4 v = *(const f32x4*)&T[rr * 132 + c4 * 4];
        *(f32x4*)&out[(size_t)(bj * 128 + p * 64 + rr) * N + bi * 128 + c4 * 4] = v;
      }
      __syncthreads();
    }
  }

  // direct tile (bi,bj) from registers
  #pragma unroll
  for (int m = 0; m < 4; ++m) {
    size_t gr0 = (size_t)(bi * 128 + wr + m * 16 + lg * 4);
    #pragma unroll
    for (int nn = 0; nn < 4; ++nn) {
      int gc = bj * 128 + wc + nn * 16 + lr;
      #pragma unroll
      for (int r = 0; r < 4; ++r)
        out[(gr0 + r) * N + gc] = acc[m][nn][r];
    }
  }
}

extern "C" void kernel_launch(void* const* d_in, const int* in_sizes, int n_in,
                              void* d_out, int out_size, void* d_ws, size_t ws_size,
                              hipStream_t stream) {
  const float* x    = (const float*)d_in[0];
  const int*   src  = (const int*)d_in[1];
  const int*   dst  = (const int*)d_in[2];
  const float* fcw  = (const float*)d_in[3];
  const float* fcb  = (const float*)d_in[4];
  const float* w1   = (const float*)d_in[5];
  const float* b1   = (const float*)d_in[6];
  const float* w2   = (const float*)d_in[7];
  const float* b2   = (const float*)d_in[8];
  const float* eps  = (const float*)d_in[9];
  const float* gamma= (const float*)d_in[10];
  const float* beta = (const float*)d_in[11];
  int n = in_sizes[0] / HID;   // 16000
  int e = in_sizes[1];         // 512000
  float* out = (float*)d_out;

  char* ws = (char*)d_ws;
  size_t off = 0;
  float* agg   = (float*)(ws + off); off += (size_t)n * HID * 4;
  float* h2a   = (float*)(ws + off); off += (size_t)n * HID * 4;
  float* h     = (float*)(ws + off); off += (size_t)n * OUT * 4;
  __bf16* G    = (__bf16*)(ws + off); off += (size_t)n * GK * 2;
  float* stats = (float*)(ws + off); off += 512;
  int* cnt     = (int*)(ws + off); off += (size_t)n * 4;
  int* offsets = (int*)(ws + off); off += (size_t)(n + 1) * 4;
  int* cursor  = (int*)(ws + off); off += (size_t)n * 4;
  int* sorted_src = (int*)(ws + off); off += (size_t)e * 4;

  hipMemsetAsync(cnt, 0, (size_t)n * 4, stream);
  hipMemsetAsync(stats, 0, 2 * OUT * 4, stream);

  hist_k<<<512, 256, 0, stream>>>(dst, cnt, e);
  scan_k<<<1, 256, 0, stream>>>(cnt, offsets, cursor, n);
  place_k<<<512, 256, 0, stream>>>(src, dst, cursor, sorted_src, e);

  agg_k<<<(n * 64 + 255) / 256, 256, 0, stream>>>(x, sorted_src, offsets, agg, n);
  mlp1_k<<<n / 16, 256, 0, stream>>>(agg, w1, b1, h2a, n);
  agg_k<<<(n * 64 + 255) / 256, 256, 0, stream>>>(h2a, sorted_src, offsets, agg, n);
  combine_k<<<n / 32, 256, 0, stream>>>(x, agg, fcw, fcb, w2, b2, eps, h, G, stats, n);
  hn_k<<<1024, 256, 0, stream>>>(h, stats, gamma, beta, out + (size_t)n * n, n);

  int nb = n >> 7;
  int nwg = nb * (nb + 1) / 2;
  gemm_k<<<nwg, 256, 0, stream>>>(G, out, n, nwg);
}